// Round 6
// baseline (106.675 us; speedup 1.0000x reference)
//
#include <hip/hip_runtime.h>

// IFNeuron forward: x[T*B, C, H, W] fp32, T=4.
// Per neuron i (within a T-slice of S = N/T floats):
//   mem = 0; for t: mem += x[t*S + i] / vth; spk = (mem >= 1); mem -= spk;
//   out[t*S + i] = spk * vth;
// Memory-bound streaming. vth == 1.0 -> multiply-by-reciprocal is bit-exact.
//
// Cache strategy (R3-R5 matrix: C-load/NT-store 80.7 < NT/NT 98.5 < C/C 106.7):
// L3 (256 MB, memory-side, writeback) can hold y (134 MB, dirty-hit every
// replay -> never reaches HBM) + most of x. All-cached thrashes (268>256),
// so NT-load 3/8 of x (50 MB from HBM each replay) and cache the rest.
// Steady-state L3 set: 84 (x) + 134 (y) = 218 MB < 256. Stores all cached.

typedef float f32x4 __attribute__((ext_vector_type(4)));

constexpr int T_STEPS = 4;
constexpr int ITEMS   = 2;   // f32x4 items per thread
constexpr int BLOCK   = 256;

__global__ __launch_bounds__(BLOCK) void if_neuron_fwd(
    const f32x4* __restrict__ x,
    const float* __restrict__ vth_p,
    f32x4*       __restrict__ y,
    int n4 /* f32x4 elems per timestep slice */,
    int nt_thresh /* i < nt_thresh -> nontemporal x loads */)
{
    const float vth = vth_p[0];
    const float inv = 1.0f / vth;   // one divide per thread; exact for vth==1.0

    const int base = blockIdx.x * (BLOCK * ITEMS) + threadIdx.x;

    // Issue all loads up front: ITEMS*T independent, per-instruction coalesced.
    f32x4 v[ITEMS][T_STEPS];
    #pragma unroll
    for (int k = 0; k < ITEMS; ++k) {
        const int i = base + k * BLOCK;
        if (i < n4) {
            if (i < nt_thresh) {
                #pragma unroll
                for (int t = 0; t < T_STEPS; ++t)
                    v[k][t] = __builtin_nontemporal_load(&x[(size_t)t * n4 + i]);
            } else {
                #pragma unroll
                for (int t = 0; t < T_STEPS; ++t)
                    v[k][t] = x[(size_t)t * n4 + i];
            }
        }
    }

    #pragma unroll
    for (int k = 0; k < ITEMS; ++k) {
        const int i = base + k * BLOCK;
        if (i >= n4) continue;
        f32x4 m = (f32x4){0.f, 0.f, 0.f, 0.f};
        #pragma unroll
        for (int t = 0; t < T_STEPS; ++t) {
            const f32x4 u = v[k][t];
            f32x4 o;

            #pragma unroll
            for (int c = 0; c < 4; ++c) {
                m[c] += u[c] * inv;
                float s = (m[c] >= 1.0f) ? 1.0f : 0.0f;
                m[c] -= s;
                o[c] = s * vth;
            }

            y[(size_t)t * n4 + i] = o;   // cached: dirty-hit in L3 every replay
        }
    }
}

extern "C" void kernel_launch(void* const* d_in, const int* in_sizes, int n_in,
                              void* d_out, int out_size, void* d_ws, size_t ws_size,
                              hipStream_t stream) {
    const float* x   = (const float*)d_in[0];
    const float* vth = (const float*)d_in[1];
    float*       out = (float*)d_out;

    const int n_total = in_sizes[0];              // 512*512*16*16 = 33,554,432
    const int slice   = n_total / T_STEPS;        // floats per timestep slice
    const int n4      = slice / 4;                // f32x4 per slice = 2,097,152

    const int nt_thresh = (int)(((long long)n4 * 3) / 8);  // 3/8 of x NT-loaded

    const int per_block = BLOCK * ITEMS;          // 512 f32x4 per block
    const int grid      = (n4 + per_block - 1) / per_block;   // 4096

    if_neuron_fwd<<<grid, BLOCK, 0, stream>>>(
        (const f32x4*)x, vth, (f32x4*)out, n4, nt_thresh);
}

// Round 8
// 81.562 us; speedup vs baseline: 1.3079x; 1.3079x over previous
//
#include <hip/hip_runtime.h>

// IFNeuron forward: x[T*B, C, H, W] fp32, T=4.
// Per neuron i (slice S = N/T): mem += x[t*S+i]/vth; spk = mem>=1; mem -= spk;
// out[t*S+i] = spk*vth.  vth==1.0 -> multiply-by-reciprocal bit-exact.
//
// Measured config matrix (timed dur, µs):
//   cached-load / nt-store   80.7  <- winner (R3)
//   nt-load    / nt-store    98.5
//   cached     / cached     106.7
//   mixed-nt   / cached     106.7
//   asm sc0sc1 store         FAIL  (inline-asm store data-reg lifetime hazard)
// R3's "268 MB WRITE" was the preceding hipMemset's dirty lines draining in
// our counter window, not NT amplification. This round: R3 structure, more
// MLP (ITEMS 2->4: 16 outstanding dwordx4 loads/thread, 2048 blocks).

typedef float f32x4 __attribute__((ext_vector_type(4)));

constexpr int T_STEPS = 4;
constexpr int ITEMS   = 4;   // f32x4 items per thread
constexpr int BLOCK   = 256;

__global__ __launch_bounds__(BLOCK) void if_neuron_fwd(
    const f32x4* __restrict__ x,
    const float* __restrict__ vth_p,
    f32x4*       __restrict__ y,
    int n4 /* f32x4 elems per timestep slice */)
{
    const float vth = vth_p[0];
    const float inv = 1.0f / vth;   // one divide per thread; exact for vth==1.0

    const int base = blockIdx.x * (BLOCK * ITEMS) + threadIdx.x;
    const bool full = (base + (ITEMS - 1) * BLOCK) < n4;  // wave-uniform here

    // Issue all loads up front: ITEMS*T independent, per-instruction coalesced.
    f32x4 v[ITEMS][T_STEPS];
    if (full) {
        #pragma unroll
        for (int k = 0; k < ITEMS; ++k) {
            const int i = base + k * BLOCK;
            #pragma unroll
            for (int t = 0; t < T_STEPS; ++t)
                v[k][t] = x[(size_t)t * n4 + i];
        }
        #pragma unroll
        for (int k = 0; k < ITEMS; ++k) {
            const int i = base + k * BLOCK;
            f32x4 m = (f32x4){0.f, 0.f, 0.f, 0.f};
            #pragma unroll
            for (int t = 0; t < T_STEPS; ++t) {
                const f32x4 u = v[k][t];
                f32x4 o;
                #pragma unroll
                for (int c = 0; c < 4; ++c) {
                    m[c] += u[c] * inv;
                    float s = (m[c] >= 1.0f) ? 1.0f : 0.0f;
                    m[c] -= s;
                    o[c] = s * vth;
                }
                __builtin_nontemporal_store(o, &y[(size_t)t * n4 + i]);
            }
        }
    } else {
        // tail path (unused for the bench shape; kept for generality)
        for (int k = 0; k < ITEMS; ++k) {
            const int i = base + k * BLOCK;
            if (i >= n4) continue;
            f32x4 m = (f32x4){0.f, 0.f, 0.f, 0.f};
            for (int t = 0; t < T_STEPS; ++t) {
                const f32x4 u = x[(size_t)t * n4 + i];
                f32x4 o;
                for (int c = 0; c < 4; ++c) {
                    m[c] += u[c] * inv;
                    float s = (m[c] >= 1.0f) ? 1.0f : 0.0f;
                    m[c] -= s;
                    o[c] = s * vth;
                }
                __builtin_nontemporal_store(o, &y[(size_t)t * n4 + i]);
            }
        }
    }
}

extern "C" void kernel_launch(void* const* d_in, const int* in_sizes, int n_in,
                              void* d_out, int out_size, void* d_ws, size_t ws_size,
                              hipStream_t stream) {
    const float* x   = (const float*)d_in[0];
    const float* vth = (const float*)d_in[1];
    float*       out = (float*)d_out;

    const int n_total = in_sizes[0];              // 512*512*16*16 = 33,554,432
    const int slice   = n_total / T_STEPS;        // floats per timestep slice
    const int n4      = slice / 4;                // f32x4 per slice = 2,097,152

    const int per_block = BLOCK * ITEMS;          // 1024 f32x4 per block
    const int grid      = (n4 + per_block - 1) / per_block;   // 2048

    if_neuron_fwd<<<grid, BLOCK, 0, stream>>>(
        (const f32x4*)x, vth, (f32x4*)out, n4);
}